// Round 1
// baseline (648.055 us; speedup 1.0000x reference)
//
#include <hip/hip_runtime.h>
#include <hip/hip_bf16.h>
#include <stdint.h>

// Problem constants
// B=2, S=2048, HID=2048, NH=16, NKV=4, DH=128
// QKV fused GEMM: M=4096, K=2048, N=3072 (Q:0..2047, K:2048..2559, V:2560..3071)

typedef __attribute__((ext_vector_type(8))) short short8;
typedef __attribute__((ext_vector_type(4))) float floatx4;
typedef __hip_bfloat16 bf16_t;

#define MFMA16x16(a, b, c) __builtin_amdgcn_mfma_f32_16x16x32_bf16(a, b, c, 0, 0, 0)

__device__ __forceinline__ void async_copy16(const void* g, void* l) {
  __builtin_amdgcn_global_load_lds(
      (const __attribute__((address_space(1))) void*)g,
      (__attribute__((address_space(3))) void*)l, 16, 0, 0);
}

__device__ __forceinline__ unsigned short bf16bits(float x) {
  bf16_t h = __float2bfloat16(x);
  return *reinterpret_cast<unsigned short*>(&h);
}

// ---------------- f32 -> bf16 convert (vectorized) ----------------
__global__ __launch_bounds__(256) void convbf_kernel(const float* __restrict__ in,
                                                     bf16_t* __restrict__ out, int n4) {
  int i = blockIdx.x * 256 + threadIdx.x;
  if (i < n4) {
    const float4 v = reinterpret_cast<const float4*>(in)[i];
    ushort4 o;
    o.x = bf16bits(v.x); o.y = bf16bits(v.y); o.z = bf16bits(v.z); o.w = bf16bits(v.w);
    reinterpret_cast<ushort4*>(out)[i] = o;
  }
}

// ---------------- weight transpose f32[K][N] -> bf16[N][K], row offset ----------------
__global__ __launch_bounds__(256) void wtrans_kernel(const float* __restrict__ W,
                                                     bf16_t* __restrict__ Wt, int N, int roff) {
  __shared__ float t[32][33];
  int k0 = blockIdx.y * 32, n0 = blockIdx.x * 32;
#pragma unroll
  for (int j = 0; j < 4; ++j)
    t[threadIdx.y + j * 8][threadIdx.x] =
        W[(size_t)(k0 + threadIdx.y + j * 8) * N + n0 + threadIdx.x];
  __syncthreads();
#pragma unroll
  for (int j = 0; j < 4; ++j) {
    int n = n0 + threadIdx.y + j * 8, k = k0 + threadIdx.x;
    Wt[(size_t)(roff + n) * 2048 + k] = __float2bfloat16(t[threadIdx.x][threadIdx.y + j * 8]);
  }
}

// ---------------- GEMM: C[M][ldc](f32) = A[M][K](bf16) x Bt[N][K](bf16)^T ----------------
// 128x128 tile, BK=64, 4 waves (2x2), each wave 64x64 (4x4 frags of 16x16x32 MFMA).
// LDS staged via global_load_lds width 16 with XOR swizzle ((row&7)<<4) applied to
// the global SOURCE address (staging) and the ds_read address (both-sides rule).
__global__ __launch_bounds__(256) void gemm_bt_kernel(const bf16_t* __restrict__ A,
                                                      const bf16_t* __restrict__ Bt,
                                                      float* __restrict__ C,
                                                      int K, int ldc) {
  __shared__ __align__(16) char smem[32768];  // A tile 16KB [128][64]bf16, B tile 16KB
  const int tid = threadIdx.x;
  const int wave = tid >> 6, lane = tid & 63;
  const int wr = wave >> 1, wc = wave & 1;
  const int l16 = lane & 15, lhi = lane >> 4;
  const int bm = blockIdx.y * 128, bn = blockIdx.x * 128;

  floatx4 acc[4][4] = {};

  for (int k0 = 0; k0 < K; k0 += 64) {
    __syncthreads();
#pragma unroll
    for (int i = 0; i < 4; ++i) {
      int chunk = i * 4 + wave;                 // 0..15
      unsigned p = (unsigned)chunk * 1024u + (unsigned)lane * 16u; // physical byte in tile
      unsigned row = p >> 7;                    // /128 bytes per row
      unsigned colg = (p & 127u) ^ ((row & 7u) << 4);  // logical byte-in-row
      const char* gA = (const char*)(A + (size_t)(bm + row) * K + k0) + colg;
      async_copy16(gA, smem + (size_t)chunk * 1024);
      const char* gB = (const char*)(Bt + (size_t)(bn + row) * K + k0) + colg;
      async_copy16(gB, smem + 16384 + (size_t)chunk * 1024);
    }
    __syncthreads();
#pragma unroll
    for (int kk = 0; kk < 2; ++kk) {
      short8 fa[4], fb[4];
#pragma unroll
      for (int mi = 0; mi < 4; ++mi) {
        unsigned row = wr * 64 + mi * 16 + l16;
        unsigned off = row * 128u + kk * 64u + lhi * 16u;
        off ^= (row & 7u) << 4;
        fa[mi] = *(const short8*)(smem + off);
      }
#pragma unroll
      for (int ni = 0; ni < 4; ++ni) {
        unsigned row = wc * 64 + ni * 16 + l16;
        unsigned off = row * 128u + kk * 64u + lhi * 16u;
        off ^= (row & 7u) << 4;
        fb[ni] = *(const short8*)(smem + 16384 + off);
      }
#pragma unroll
      for (int mi = 0; mi < 4; ++mi)
#pragma unroll
        for (int ni = 0; ni < 4; ++ni)
          acc[mi][ni] = MFMA16x16(fa[mi], fb[ni], acc[mi][ni]);
    }
  }
#pragma unroll
  for (int mi = 0; mi < 4; ++mi)
#pragma unroll
    for (int ni = 0; ni < 4; ++ni)
#pragma unroll
      for (int r = 0; r < 4; ++r) {
        int row = bm + wr * 64 + mi * 16 + lhi * 4 + r;
        int col = bn + wc * 64 + ni * 16 + l16;
        C[(size_t)row * ldc + col] = acc[mi][ni][r];
      }
}

// ---------------- RMSNorm + RoPE + relayout for Q and K ----------------
// One wave per (row, unit). units 0..15: Q head; 16..19: K head.
// lane handles d=lane and d=lane+64 (rotate-half pair in-lane).
__global__ __launch_bounds__(256) void qknorm_rope_kernel(
    const float* __restrict__ Cqkv, const float* __restrict__ cosT,
    const float* __restrict__ sinT, const float* __restrict__ qw,
    const float* __restrict__ kw, bf16_t* __restrict__ Qa, bf16_t* __restrict__ Ka) {
  int wave = threadIdx.x >> 6, lane = threadIdx.x & 63;
  int task = blockIdx.x * 4 + wave;  // 4096*20 tasks
  int unit = task % 20;
  int row = task / 20;               // b*2048 + s
  int b = row >> 11, s = row & 2047;
  const float* src;
  const float* w;
  bf16_t* dst;
  if (unit < 16) {
    src = Cqkv + (size_t)row * 3072 + unit * 128;
    w = qw;
    dst = Qa + ((size_t)(b * 16 + unit) * 2048 + s) * 128;
  } else {
    int kh = unit - 16;
    src = Cqkv + (size_t)row * 3072 + 2048 + kh * 128;
    w = kw;
    dst = Ka + ((size_t)(b * 4 + kh) * 2048 + s) * 128;
  }
  float x1 = src[lane], x2 = src[lane + 64];
  float ss = x1 * x1 + x2 * x2;
#pragma unroll
  for (int off = 1; off < 64; off <<= 1) ss += __shfl_xor(ss, off, 64);
  float inv = rsqrtf(ss * (1.f / 128.f) + 1e-6f);
  x1 = x1 * inv * w[lane];
  x2 = x2 * inv * w[lane + 64];
  float c1 = cosT[(size_t)s * 128 + lane], c2 = cosT[(size_t)s * 128 + lane + 64];
  float s1 = sinT[(size_t)s * 128 + lane], s2 = sinT[(size_t)s * 128 + lane + 64];
  dst[lane] = __float2bfloat16(x1 * c1 - x2 * s1);
  dst[lane + 64] = __float2bfloat16(x2 * c2 + x1 * s2);
}

// ---------------- V transpose: Cqkv[.,2560+kh*128+d] f32 -> Vt[b][kh][d][s] bf16 --------
__global__ __launch_bounds__(256) void vtrans_kernel(const float* __restrict__ Cqkv,
                                                     bf16_t* __restrict__ Vt) {
  __shared__ float t[32][33];
  int bk = blockIdx.z;
  int b = bk >> 2, kh = bk & 3;
  int s0 = blockIdx.x * 32, d0 = blockIdx.y * 32;
  const float* src = Cqkv + (size_t)(b * 2048) * 3072 + 2560 + kh * 128;
#pragma unroll
  for (int j = 0; j < 4; ++j)
    t[threadIdx.y + j * 8][threadIdx.x] =
        src[(size_t)(s0 + threadIdx.y + j * 8) * 3072 + d0 + threadIdx.x];
  __syncthreads();
  bf16_t* dst = Vt + (size_t)(b * 4 + kh) * 128 * 2048;
#pragma unroll
  for (int j = 0; j < 4; ++j) {
    int d = d0 + threadIdx.y + j * 8, s = s0 + threadIdx.x;
    dst[(size_t)d * 2048 + s] = __float2bfloat16(t[threadIdx.x][threadIdx.y + j * 8]);
  }
}

// ---------------- Flash attention (causal, GQA) ----------------
// 1 wave per 16-row Q tile. KV chunks of 32. Qa[B*NH][S][DH], Ka[B*NKV][S][DH],
// Vt[B*NKV][DH][S]. Output attn[B*S][NH*DH] bf16.
__global__ __launch_bounds__(256) void flash_kernel(const bf16_t* __restrict__ Qa,
                                                    const bf16_t* __restrict__ Ka,
                                                    const bf16_t* __restrict__ Vt,
                                                    bf16_t* __restrict__ attnO) {
  __shared__ __align__(16) bf16_t Plds[4][16][32];
  const int wave = threadIdx.x >> 6, lane = threadIdx.x & 63;
  const int l16 = lane & 15, lhi = lane >> 4;
  int task = blockIdx.x * 4 + wave;  // B*NH*(S/16) = 4096
  int qt = task & 127, bh = task >> 7;
  int h = bh & 15, b = bh >> 4;
  int kh = h >> 2;
  int q0 = qt << 4;

  const bf16_t* Qb = Qa + ((size_t)bh * 2048 + q0) * 128;
  const bf16_t* Kb = Ka + ((size_t)(b * 4 + kh) * 2048) * 128;
  const bf16_t* Vb = Vt + ((size_t)(b * 4 + kh) * 128) * 2048;

  short8 qf[4];
#pragma unroll
  for (int kk = 0; kk < 4; ++kk)
    qf[kk] = *(const short8*)(Qb + (size_t)l16 * 128 + kk * 32 + lhi * 8);

  floatx4 o[8] = {};
  float m[4], l[4];
#pragma unroll
  for (int r = 0; r < 4; ++r) { m[r] = -1e30f; l[r] = 0.f; }

  const float scale = 0.088388347648318447f;  // 1/sqrt(128)
  int nch = (q0 + 47) >> 5;
  for (int c = 0; c < nch; ++c) {
    int kc0 = c << 5;
    floatx4 s0 = {0.f, 0.f, 0.f, 0.f}, s1 = {0.f, 0.f, 0.f, 0.f};
#pragma unroll
    for (int kk = 0; kk < 4; ++kk) {
      short8 b0 = *(const short8*)(Kb + (size_t)(kc0 + l16) * 128 + kk * 32 + lhi * 8);
      short8 b1 = *(const short8*)(Kb + (size_t)(kc0 + 16 + l16) * 128 + kk * 32 + lhi * 8);
      s0 = MFMA16x16(qf[kk], b0, s0);
      s1 = MFMA16x16(qf[kk], b1, s1);
    }
#pragma unroll
    for (int r = 0; r < 4; ++r) {
      int qrow = q0 + lhi * 4 + r;
      float v0 = s0[r] * scale + ((kc0 + l16) > qrow ? -1e9f : 0.f);
      float v1 = s1[r] * scale + ((kc0 + 16 + l16) > qrow ? -1e9f : 0.f);
      float mx = fmaxf(v0, v1);
#pragma unroll
      for (int off = 1; off < 16; off <<= 1) mx = fmaxf(mx, __shfl_xor(mx, off, 64));
      float mnew = fmaxf(m[r], mx);
      float corr = __expf(m[r] - mnew);
      float p0 = __expf(v0 - mnew), p1 = __expf(v1 - mnew);
      float ps = p0 + p1;
#pragma unroll
      for (int off = 1; off < 16; off <<= 1) ps += __shfl_xor(ps, off, 64);
      l[r] = l[r] * corr + ps;
      m[r] = mnew;
      int prow = lhi * 4 + r;
      Plds[wave][prow][l16] = __float2bfloat16(p0);
      Plds[wave][prow][l16 + 16] = __float2bfloat16(p1);
#pragma unroll
      for (int f = 0; f < 8; ++f) o[f][r] *= corr;
    }
    // P fragment (a-frag layout): lane reads row l16, keys lhi*8..+7
    short8 pf = *(const short8*)&Plds[wave][l16][lhi * 8];
#pragma unroll
    for (int f = 0; f < 8; ++f) {
      short8 vf = *(const short8*)(Vb + (size_t)(f * 16 + l16) * 2048 + kc0 + lhi * 8);
      o[f] = MFMA16x16(pf, vf, o[f]);
    }
  }
#pragma unroll
  for (int r = 0; r < 4; ++r) {
    float inv = 1.f / l[r];
    int row = q0 + lhi * 4 + r;
    size_t base = ((size_t)(b * 2048) + row) * 2048 + h * 128;
#pragma unroll
    for (int f = 0; f < 8; ++f)
      attnO[base + f * 16 + l16] = __float2bfloat16(o[f][r] * inv);
  }
}

// ---------------- launch ----------------
extern "C" void kernel_launch(void* const* d_in, const int* in_sizes, int n_in,
                              void* d_out, int out_size, void* d_ws, size_t ws_size,
                              hipStream_t stream) {
  const float* hs = (const float*)d_in[0];
  // d_in[1] = attention_mask (pure causal -1e9; applied analytically in flash)
  const float* cosT = (const float*)d_in[2];
  const float* sinT = (const float*)d_in[3];
  const float* Wq = (const float*)d_in[4];
  const float* Wk = (const float*)d_in[5];
  const float* Wv = (const float*)d_in[6];
  const float* Wo = (const float*)d_in[7];
  const float* qw = (const float*)d_in[8];
  const float* kw = (const float*)d_in[9];
  float* out = (float*)d_out;

  char* ws = (char*)d_ws;
  size_t off = 0;
  auto alloc = [&](size_t bytes) {
    char* p = ws + off;
    off += (bytes + 255) & ~(size_t)255;
    return p;
  };
  bf16_t* hsb  = (bf16_t*)alloc((size_t)4096 * 2048 * 2);   // hidden bf16
  bf16_t* wqkv = (bf16_t*)alloc((size_t)3072 * 2048 * 2);   // [N=3072][K=2048]
  bf16_t* wot  = (bf16_t*)alloc((size_t)2048 * 2048 * 2);   // Wo^T
  float*  cqkv = (float*)alloc((size_t)4096 * 3072 * 4);    // QKV gemm out (f32)
  bf16_t* qa   = (bf16_t*)alloc((size_t)2 * 16 * 2048 * 128 * 2);
  bf16_t* ka   = (bf16_t*)alloc((size_t)2 * 4 * 2048 * 128 * 2);
  bf16_t* vt   = (bf16_t*)alloc((size_t)2 * 4 * 2048 * 128 * 2);
  bf16_t* attn = (bf16_t*)cqkv;  // reuse (cqkv dead after relayout kernels)

  convbf_kernel<<<8192, 256, 0, stream>>>(hs, hsb, 2097152);
  dim3 tb(32, 8);
  wtrans_kernel<<<dim3(64, 64), tb, 0, stream>>>(Wq, wqkv, 2048, 0);
  wtrans_kernel<<<dim3(16, 64), tb, 0, stream>>>(Wk, wqkv, 512, 2048);
  wtrans_kernel<<<dim3(16, 64), tb, 0, stream>>>(Wv, wqkv, 512, 2560);
  wtrans_kernel<<<dim3(64, 64), tb, 0, stream>>>(Wo, wot, 2048, 0);
  gemm_bt_kernel<<<dim3(24, 32), 256, 0, stream>>>(hsb, wqkv, cqkv, 2048, 3072);
  qknorm_rope_kernel<<<20480, 256, 0, stream>>>(cqkv, cosT, sinT, qw, kw, qa, ka);
  vtrans_kernel<<<dim3(64, 4, 8), tb, 0, stream>>>(cqkv, vt);
  flash_kernel<<<1024, 256, 0, stream>>>(qa, ka, vt, attn);
  gemm_bt_kernel<<<dim3(16, 32), 256, 0, stream>>>(attn, wot, out, 2048, 2048);
}

// Round 6
// 285.932 us; speedup vs baseline: 2.2665x; 2.2665x over previous
//
#include <hip/hip_runtime.h>
#include <hip/hip_bf16.h>
#include <stdint.h>

// Problem constants
// B=2, S=2048, HID=2048, NH=16, NKV=4, DH=128
// QKV fused GEMM: M=4096, K=2048, N=3072 (Q:0..2047, K:2048..2559, V:2560..3071)

typedef __attribute__((ext_vector_type(8))) short short8;
typedef __attribute__((ext_vector_type(4))) float floatx4;
typedef __hip_bfloat16 bf16_t;

#define MFMA16x16(a, b, c) __builtin_amdgcn_mfma_f32_16x16x32_bf16(a, b, c, 0, 0, 0)

__device__ __forceinline__ void async_copy16(const void* g, void* l) {
  __builtin_amdgcn_global_load_lds(
      (const __attribute__((address_space(1))) void*)g,
      (__attribute__((address_space(3))) void*)l, 16, 0, 0);
}

__device__ __forceinline__ unsigned short bf16bits(float x) {
  bf16_t h = __float2bfloat16(x);
  return *reinterpret_cast<unsigned short*>(&h);
}

// ---------------- f32 -> bf16 convert (vectorized) ----------------
__global__ __launch_bounds__(256) void convbf_kernel(const float* __restrict__ in,
                                                     bf16_t* __restrict__ out, int n4) {
  int i = blockIdx.x * 256 + threadIdx.x;
  if (i < n4) {
    const float4 v = reinterpret_cast<const float4*>(in)[i];
    ushort4 o;
    o.x = bf16bits(v.x); o.y = bf16bits(v.y); o.z = bf16bits(v.z); o.w = bf16bits(v.w);
    reinterpret_cast<ushort4*>(out)[i] = o;
  }
}

// ---------------- weight transpose f32[K][N] -> bf16[N][K], row offset ----------------
__global__ __launch_bounds__(256) void wtrans_kernel(const float* __restrict__ W,
                                                     bf16_t* __restrict__ Wt, int N, int roff) {
  __shared__ float t[32][33];
  int k0 = blockIdx.y * 32, n0 = blockIdx.x * 32;
#pragma unroll
  for (int j = 0; j < 4; ++j)
    t[threadIdx.y + j * 8][threadIdx.x] =
        W[(size_t)(k0 + threadIdx.y + j * 8) * N + n0 + threadIdx.x];
  __syncthreads();
#pragma unroll
  for (int j = 0; j < 4; ++j) {
    int n = n0 + threadIdx.y + j * 8, k = k0 + threadIdx.x;
    Wt[(size_t)(roff + n) * 2048 + k] = __float2bfloat16(t[threadIdx.x][threadIdx.y + j * 8]);
  }
}

// ---------------- GEMM: C[M][ldc](f32) = A[M][K](bf16) x Bt[N][K](bf16)^T ----------------
__global__ __launch_bounds__(256) void gemm_bt_kernel(const bf16_t* __restrict__ A,
                                                      const bf16_t* __restrict__ Bt,
                                                      float* __restrict__ C,
                                                      int K, int ldc) {
  __shared__ __align__(16) char smem[32768];
  const int tid = threadIdx.x;
  const int wave = tid >> 6, lane = tid & 63;
  const int wr = wave >> 1, wc = wave & 1;
  const int l16 = lane & 15, lhi = lane >> 4;
  const int bm = blockIdx.y * 128, bn = blockIdx.x * 128;

  floatx4 acc[4][4] = {};

  for (int k0 = 0; k0 < K; k0 += 64) {
    __syncthreads();
#pragma unroll
    for (int i = 0; i < 4; ++i) {
      int chunk = i * 4 + wave;
      unsigned p = (unsigned)chunk * 1024u + (unsigned)lane * 16u;
      unsigned row = p >> 7;
      unsigned colg = (p & 127u) ^ ((row & 7u) << 4);
      const char* gA = (const char*)(A + (size_t)(bm + row) * K + k0) + colg;
      async_copy16(gA, smem + (size_t)chunk * 1024);
      const char* gB = (const char*)(Bt + (size_t)(bn + row) * K + k0) + colg;
      async_copy16(gB, smem + 16384 + (size_t)chunk * 1024);
    }
    __syncthreads();
#pragma unroll
    for (int kk = 0; kk < 2; ++kk) {
      short8 fa[4], fb[4];
#pragma unroll
      for (int mi = 0; mi < 4; ++mi) {
        unsigned row = wr * 64 + mi * 16 + l16;
        unsigned off = row * 128u + kk * 64u + lhi * 16u;
        off ^= (row & 7u) << 4;
        fa[mi] = *(const short8*)(smem + off);
      }
#pragma unroll
      for (int ni = 0; ni < 4; ++ni) {
        unsigned row = wc * 64 + ni * 16 + l16;
        unsigned off = row * 128u + kk * 64u + lhi * 16u;
        off ^= (row & 7u) << 4;
        fb[ni] = *(const short8*)(smem + 16384 + off);
      }
#pragma unroll
      for (int mi = 0; mi < 4; ++mi)
#pragma unroll
        for (int ni = 0; ni < 4; ++ni)
          acc[mi][ni] = MFMA16x16(fa[mi], fb[ni], acc[mi][ni]);
    }
  }
#pragma unroll
  for (int mi = 0; mi < 4; ++mi)
#pragma unroll
    for (int ni = 0; ni < 4; ++ni)
#pragma unroll
      for (int r = 0; r < 4; ++r) {
        int row = bm + wr * 64 + mi * 16 + lhi * 4 + r;
        int col = bn + wc * 64 + ni * 16 + l16;
        C[(size_t)row * ldc + col] = acc[mi][ni][r];
      }
}

// ---------------- RMSNorm + RoPE + relayout for Q and K ----------------
__global__ __launch_bounds__(256) void qknorm_rope_kernel(
    const float* __restrict__ Cqkv, const float* __restrict__ cosT,
    const float* __restrict__ sinT, const float* __restrict__ qw,
    const float* __restrict__ kw, bf16_t* __restrict__ Qa, bf16_t* __restrict__ Ka) {
  int wave = threadIdx.x >> 6, lane = threadIdx.x & 63;
  int task = blockIdx.x * 4 + wave;
  int unit = task % 20;
  int row = task / 20;
  int b = row >> 11, s = row & 2047;
  const float* src;
  const float* w;
  bf16_t* dst;
  if (unit < 16) {
    src = Cqkv + (size_t)row * 3072 + unit * 128;
    w = qw;
    dst = Qa + ((size_t)(b * 16 + unit) * 2048 + s) * 128;
  } else {
    int kh = unit - 16;
    src = Cqkv + (size_t)row * 3072 + 2048 + kh * 128;
    w = kw;
    dst = Ka + ((size_t)(b * 4 + kh) * 2048 + s) * 128;
  }
  float x1 = src[lane], x2 = src[lane + 64];
  float ss = x1 * x1 + x2 * x2;
#pragma unroll
  for (int off = 1; off < 64; off <<= 1) ss += __shfl_xor(ss, off, 64);
  float inv = rsqrtf(ss * (1.f / 128.f) + 1e-6f);
  x1 = x1 * inv * w[lane];
  x2 = x2 * inv * w[lane + 64];
  float c1 = cosT[(size_t)s * 128 + lane], c2 = cosT[(size_t)s * 128 + lane + 64];
  float s1 = sinT[(size_t)s * 128 + lane], s2 = sinT[(size_t)s * 128 + lane + 64];
  dst[lane] = __float2bfloat16(x1 * c1 - x2 * s1);
  dst[lane + 64] = __float2bfloat16(x2 * c2 + x1 * s2);
}

// ---------------- V transpose: Cqkv f32 -> Vt[b][kh][d][s] bf16 ----------------
__global__ __launch_bounds__(256) void vtrans_kernel(const float* __restrict__ Cqkv,
                                                     bf16_t* __restrict__ Vt) {
  __shared__ float t[32][33];
  int bk = blockIdx.z;
  int b = bk >> 2, kh = bk & 3;
  int s0 = blockIdx.x * 32, d0 = blockIdx.y * 32;
  const float* src = Cqkv + (size_t)(b * 2048) * 3072 + 2560 + kh * 128;
#pragma unroll
  for (int j = 0; j < 4; ++j)
    t[threadIdx.y + j * 8][threadIdx.x] =
        src[(size_t)(s0 + threadIdx.y + j * 8) * 3072 + d0 + threadIdx.x];
  __syncthreads();
  bf16_t* dst = Vt + (size_t)(b * 4 + kh) * 128 * 2048;
#pragma unroll
  for (int j = 0; j < 4; ++j) {
    int d = d0 + threadIdx.y + j * 8, s = s0 + threadIdx.x;
    dst[(size_t)d * 2048 + s] = __float2bfloat16(t[threadIdx.x][threadIdx.y + j * 8]);
  }
}

// ---------------- Flash attention v2 (causal, GQA) ----------------
// Block = 4 waves, each wave 32 Q-rows -> 128 rows/block. KV chunk = 64 keys.
// K double-buffered + V single-buffered in LDS (XOR-swizzled, staged via
// global_load_lds w16, shared by all 4 waves). P transposed via per-wave
// swizzled LDS buffer. Online softmax w/ defer-max (THR=8).
// LDS: K0@0 (16K), K1@16K, V@32K (16K), P@48K (4 x 4K) = 64KB total.
__global__ __launch_bounds__(256, 2) void flash_kernel(const bf16_t* __restrict__ Qa,
                                                       const bf16_t* __restrict__ Ka,
                                                       const bf16_t* __restrict__ Vt,
                                                       bf16_t* __restrict__ attnO) {
  __shared__ __align__(16) char smem[65536];
  const int tid = threadIdx.x;
  const int wave = tid >> 6, lane = tid & 63;
  const int l16 = lane & 15, lhi = lane >> 4;
  const int bid = blockIdx.x;          // 512 blocks
  const int bh = bid & 31;             // b*16 + h
  const int qb = 15 - (bid >> 5);      // heavy q-blocks first
  const int h = bh & 15, b = bh >> 4;
  const int kh = h >> 2;
  const int q0b = qb << 7;
  const int q0w = q0b + wave * 32;

  const bf16_t* Qb = Qa + ((size_t)bh * 2048 + q0w) * 128;
  const bf16_t* Kb = Ka + (size_t)(b * 4 + kh) * 2048 * 128;
  const bf16_t* Vb = Vt + (size_t)(b * 4 + kh) * 128 * 2048;

  char* K0 = smem;
  char* K1 = smem + 16384;
  char* Vl = smem + 32768;
  char* Pl = smem + 49152 + wave * 4096;  // per-wave [32][64] bf16, XOR-swizzled

  // Q fragments in registers: rows q0w + rt*16 + l16, dims kk*32 + lhi*8
  short8 qf[2][4];
#pragma unroll
  for (int rt = 0; rt < 2; ++rt)
#pragma unroll
    for (int kk = 0; kk < 4; ++kk)
      qf[rt][kk] = *(const short8*)(Qb + (size_t)(rt * 16 + l16) * 128 + kk * 32 + lhi * 8);

  floatx4 o[2][8] = {};
  float m[2][4], l[2][4];
#pragma unroll
  for (int rt = 0; rt < 2; ++rt)
#pragma unroll
    for (int r = 0; r < 4; ++r) { m[rt][r] = -1e30f; l[rt][r] = 0.f; }

  const float scale = 0.088388347648318447f;  // 1/sqrt(128)
  const float THR = 8.0f;
  const int nch = 2 * qb + 2;
  const unsigned pswz_rd = (unsigned)(l16 & 7) << 4;

  // prologue: stage K chunk 0 into K0
#pragma unroll
  for (int it = 0; it < 4; ++it) {
    unsigned base = (unsigned)(it * 4 + wave) * 1024u;
    unsigned p = base + (unsigned)lane * 16u;
    unsigned row = p >> 8, col = p & 255u;
    unsigned gcol = col ^ ((row & 7u) << 4);
    async_copy16((const char*)(Kb + (size_t)row * 128) + gcol, K0 + base);
  }
  __syncthreads();

  int cur = 0;
  for (int c = 0; c < nch; ++c) {
    const int kc0 = c << 6;
    char* Kc = cur ? K1 : K0;
    char* Kn = cur ? K0 : K1;
    // stage V_c and (if any) K_{c+1}: in flight across QK + softmax
#pragma unroll
    for (int it = 0; it < 4; ++it) {
      unsigned base = (unsigned)(it * 4 + wave) * 1024u;
      unsigned p = base + (unsigned)lane * 16u;
      unsigned row = p >> 7, col = p & 127u;
      unsigned gcol = col ^ ((row & 7u) << 4);
      async_copy16((const char*)(Vb + (size_t)row * 2048 + kc0) + gcol, Vl + base);
    }
    if (c + 1 < nch) {
#pragma unroll
      for (int it = 0; it < 4; ++it) {
        unsigned base = (unsigned)(it * 4 + wave) * 1024u;
        unsigned p = base + (unsigned)lane * 16u;
        unsigned row = p >> 8, col = p & 255u;
        unsigned gcol = col ^ ((row & 7u) << 4);
        async_copy16((const char*)(Kb + (size_t)(kc0 + 64 + row) * 128) + gcol, Kn + base);
      }
    }

    // QK^T from K[cur]
    floatx4 s[2][4] = {};
#pragma unroll
    for (int kk = 0; kk < 4; ++kk) {
#pragma unroll
      for (int kt = 0; kt < 4; ++kt) {
        unsigned off = (unsigned)(kt * 16 + l16) * 256u +
                       (((unsigned)(kk * 64 + lhi * 16)) ^ pswz_rd);
        short8 kf = *(const short8*)(Kc + off);
        s[0][kt] = MFMA16x16(qf[0][kk], kf, s[0][kt]);
        s[1][kt] = MFMA16x16(qf[1][kk], kf, s[1][kt]);
      }
    }

    // online softmax (per row-tile), defer-max
#pragma unroll
    for (int rt = 0; rt < 2; ++rt) {
      float mx[4];
#pragma unroll
      for (int r = 0; r < 4; ++r) {
        int qrow = q0w + rt * 16 + lhi * 4 + r;
#pragma unroll
        for (int kt = 0; kt < 4; ++kt) {
          float v = s[rt][kt][r] * scale + ((kc0 + kt * 16 + l16) > qrow ? -1e9f : 0.f);
          s[rt][kt][r] = v;
        }
        float t = fmaxf(fmaxf(s[rt][0][r], s[rt][1][r]), fmaxf(s[rt][2][r], s[rt][3][r]));
#pragma unroll
        for (int off = 1; off < 16; off <<= 1) t = fmaxf(t, __shfl_xor(t, off, 64));
        mx[r] = t;
      }
      bool grow = (mx[0] > m[rt][0] + THR) | (mx[1] > m[rt][1] + THR) |
                  (mx[2] > m[rt][2] + THR) | (mx[3] > m[rt][3] + THR);
      if (__any(grow)) {
#pragma unroll
        for (int r = 0; r < 4; ++r) {
          float mn = fmaxf(m[rt][r], mx[r]);
          float corr = __expf(m[rt][r] - mn);
          m[rt][r] = mn;
          l[rt][r] *= corr;
#pragma unroll
          for (int f = 0; f < 8; ++f) o[rt][f][r] *= corr;
        }
      }
#pragma unroll
      for (int r = 0; r < 4; ++r) {
        int prow = rt * 16 + lhi * 4 + r;
        unsigned ps_w = (unsigned)(prow & 7) << 4;
        float ps = 0.f;
#pragma unroll
        for (int kt = 0; kt < 4; ++kt) {
          float p = __expf(s[rt][kt][r] - m[rt][r]);
          ps += p;
          unsigned off = (unsigned)prow * 128u + ((((unsigned)(kt * 16 + l16)) * 2u) ^ ps_w);
          *(unsigned short*)(Pl + off) = bf16bits(p);
        }
#pragma unroll
        for (int off = 1; off < 16; off <<= 1) ps += __shfl_xor(ps, off, 64);
        l[rt][r] += ps;
      }
    }

    __syncthreads();  // drains V_c + K_{c+1} staging (vmcnt 0), all waves aligned

    // PV from Vl + Pl
#pragma unroll
    for (int ks = 0; ks < 2; ++ks) {
      short8 vf[8];
#pragma unroll
      for (int f = 0; f < 8; ++f) {
        unsigned off = (unsigned)(f * 16 + l16) * 128u +
                       (((unsigned)(ks * 64 + lhi * 16)) ^ pswz_rd);
        vf[f] = *(const short8*)(Vl + off);
      }
#pragma unroll
      for (int rt = 0; rt < 2; ++rt) {
        unsigned off = (unsigned)(rt * 16 + l16) * 128u +
                       (((unsigned)(ks * 64 + lhi * 16)) ^ pswz_rd);
        short8 pf = *(const short8*)(Pl + off);
#pragma unroll
        for (int f = 0; f < 8; ++f) o[rt][f] = MFMA16x16(pf, vf[f], o[rt][f]);
      }
    }

    __syncthreads();  // all waves done with Vl/K[cur] before next stage
    cur ^= 1;
  }

  // epilogue
#pragma unroll
  for (int rt = 0; rt < 2; ++rt)
#pragma unroll
    for (int r = 0; r < 4; ++r) {
      float inv = 1.f / l[rt][r];
      int row = q0w + rt * 16 + lhi * 4 + r;
      size_t base = ((size_t)(b * 2048) + row) * 2048 + h * 128;
#pragma unroll
      for (int f = 0; f < 8; ++f)
        attnO[base + f * 16 + l16] = __float2bfloat16(o[rt][f][r] * inv);
    }
}

// ---------------- launch ----------------
extern "C" void kernel_launch(void* const* d_in, const int* in_sizes, int n_in,
                              void* d_out, int out_size, void* d_ws, size_t ws_size,
                              hipStream_t stream) {
  const float* hs = (const float*)d_in[0];
  const float* cosT = (const float*)d_in[2];
  const float* sinT = (const float*)d_in[3];
  const float* Wq = (const float*)d_in[4];
  const float* Wk = (const float*)d_in[5];
  const float* Wv = (const float*)d_in[6];
  const float* Wo = (const float*)d_in[7];
  const float* qw = (const float*)d_in[8];
  const float* kw = (const float*)d_in[9];
  float* out = (float*)d_out;

  char* ws = (char*)d_ws;
  size_t off = 0;
  auto alloc = [&](size_t bytes) {
    char* p = ws + off;
    off += (bytes + 255) & ~(size_t)255;
    return p;
  };
  bf16_t* hsb  = (bf16_t*)alloc((size_t)4096 * 2048 * 2);
  bf16_t* wqkv = (bf16_t*)alloc((size_t)3072 * 2048 * 2);
  bf16_t* wot  = (bf16_t*)alloc((size_t)2048 * 2048 * 2);
  float*  cqkv = (float*)alloc((size_t)4096 * 3072 * 4);
  bf16_t* qa   = (bf16_t*)alloc((size_t)2 * 16 * 2048 * 128 * 2);
  bf16_t* ka   = (bf16_t*)alloc((size_t)2 * 4 * 2048 * 128 * 2);
  bf16_t* vt   = (bf16_t*)alloc((size_t)2 * 4 * 2048 * 128 * 2);
  bf16_t* attn = (bf16_t*)cqkv;

  convbf_kernel<<<8192, 256, 0, stream>>>(hs, hsb, 2097152);
  dim3 tb(32, 8);
  wtrans_kernel<<<dim3(64, 64), tb, 0, stream>>>(Wq, wqkv, 2048, 0);
  wtrans_kernel<<<dim3(16, 64), tb, 0, stream>>>(Wk, wqkv, 512, 2048);
  wtrans_kernel<<<dim3(16, 64), tb, 0, stream>>>(Wv, wqkv, 512, 2560);
  wtrans_kernel<<<dim3(64, 64), tb, 0, stream>>>(Wo, wot, 2048, 0);
  gemm_bt_kernel<<<dim3(24, 32), 256, 0, stream>>>(hsb, wqkv, cqkv, 2048, 3072);
  qknorm_rope_kernel<<<20480, 256, 0, stream>>>(cqkv, cosT, sinT, qw, kw, qa, ka);
  vtrans_kernel<<<dim3(64, 4, 8), tb, 0, stream>>>(cqkv, vt);
  flash_kernel<<<512, 256, 0, stream>>>(qa, ka, vt, attn);
  gemm_bt_kernel<<<dim3(16, 32), 256, 0, stream>>>(attn, wot, out, 2048, 2048);
}